// Round 2
// baseline (875.479 us; speedup 1.0000x reference)
//
#include <hip/hip_runtime.h>

#define LRELU(v) ((v) > 0.0f ? (v) : 0.01f * (v))
#define SENTINEL ((int)0x80000000)

// Order-preserving map float -> int32 (involution), so signed atomicMax works.
__device__ __forceinline__ int f2ord(float f) {
    int i = __float_as_int(f);
    return (i >= 0) ? i : (int)(0x80000000u - (unsigned int)i);
}
__device__ __forceinline__ float ord2f(int m) {
    int i = (m >= 0) ? m : (int)(0x80000000u - (unsigned int)m);
    return __int_as_float(i);
}

__global__ void fill_i32(int* __restrict__ p, int n, int v) {
    int i = blockIdx.x * blockDim.x + threadIdx.x;
    if (i < n) p[i] = v;
}

// out[r, c] = lrelu(sum_k x[r,k] * W[k,c] + b[c]), c in [0,32)
__global__ void lin_lrelu(const float* __restrict__ x, const float* __restrict__ W,
                          const float* __restrict__ b, float* __restrict__ out,
                          int rows, int cin) {
    int idx = blockIdx.x * blockDim.x + threadIdx.x;
    if (idx >= rows * 32) return;
    int c = idx & 31;
    int r = idx >> 5;
    float acc = b[c];
    for (int k = 0; k < cin; ++k)
        acc = fmaf(x[r * cin + k], W[k * 32 + c], acc);
    out[idx] = LRELU(acc);
}

// One thread per (edge, batch, channel). maxb holds f2ord-mapped running max.
__global__ void scatter_max(const float* __restrict__ xsrc, const float* __restrict__ xdst,
                            const int* __restrict__ edges, int E, int Ns, int Nd,
                            int* __restrict__ maxb) {
    int idx = blockIdx.x * blockDim.x + threadIdx.x;
    if (idx >= E * 128) return;
    int c = idx & 31;
    int b = (idx >> 5) & 3;
    int e = idx >> 7;
    int s = edges[e];        // row 0 of [2, E]
    int d = edges[E + e];    // row 1
    float diff = xdst[(b * Nd + d) * 32 + c] - xsrc[(b * Ns + s) * 32 + c];
    atomicMax(maxb + (b * Nd + d) * 32 + c, f2ord(diff));
}

// out[row, c] = xdst[row, c] + lrelu(sum_k h[row,k] * W[k,c] + bias[c])
// h = [xdst(32) | maxes(32)], maxes sentinel (empty segment) -> 0.
// Safe for out == xdst (each thread reads its own element before writing).
__global__ void mlp_res(const float* __restrict__ xdst, const int* __restrict__ maxb,
                        const float* __restrict__ W, const float* __restrict__ bias,
                        float* __restrict__ out, int rows) {
    __shared__ float sW[2048];      // 64 x 32
    __shared__ float sh[8][64];     // 8 node-rows per 256-thread block
    int t = threadIdx.x;
    for (int i = t; i < 2048; i += 256) sW[i] = W[i];
    int c = t & 31;
    int g = t >> 5;
    int row = blockIdx.x * 8 + g;
    float xv = 0.0f;
    if (row < rows) {
        xv = xdst[row * 32 + c];
        int m = maxb[row * 32 + c];
        sh[g][c] = xv;
        sh[g][32 + c] = (m == SENTINEL) ? 0.0f : ord2f(m);
    }
    __syncthreads();
    if (row >= rows) return;
    float acc = bias[c];
#pragma unroll
    for (int k = 0; k < 64; ++k)
        acc = fmaf(sh[g][k], sW[k * 32 + c], acc);
    out[row * 32 + c] = xv + LRELU(acc);
}

extern "C" void kernel_launch(void* const* d_in, const int* in_sizes, int n_in,
                              void* d_out, int out_size, void* d_ws, size_t ws_size,
                              hipStream_t stream) {
    const float* x_f = (const float*)d_in[0];
    const float* x_e = (const float*)d_in[1];
    const float* x_v = (const float*)d_in[2];
    // d_in[3] = index_id (identity arange) — intentionally unused
    const int* fe = (const int*)d_in[4];
    const int* ev = (const int*)d_in[5];
    const int* ff = (const int*)d_in[6];
    const int* ef = (const int*)d_in[7];
    const int* ve = (const int*)d_in[8];
    const float* Wf = (const float*)d_in[9];
    const float* bf = (const float*)d_in[10];
    const float* We = (const float*)d_in[11];
    const float* be = (const float*)d_in[12];
    const float* Wv = (const float*)d_in[13];
    const float* bv = (const float*)d_in[14];
    const float* W_f2e = (const float*)d_in[15];
    const float* b_f2e = (const float*)d_in[16];
    const float* W_e2v = (const float*)d_in[17];
    const float* b_e2v = (const float*)d_in[18];
    const float* W_ff  = (const float*)d_in[19];
    const float* b_ff  = (const float*)d_in[20];
    const float* W_e2f = (const float*)d_in[21];
    const float* b_e2f = (const float*)d_in[22];
    const float* W_v2e = (const float*)d_in[23];
    const float* b_v2e = (const float*)d_in[24];

    const int B = 4, Nf = 40000, Ne = 80000, Nv = 40000;
    const int E_fe = in_sizes[4] / 2;   // 160000
    const int E_ev = in_sizes[5] / 2;   // 160000
    const int E_ff = in_sizes[6] / 2;   // 240000
    const int E_ef = in_sizes[7] / 2;   // 160000
    const int E_ve = in_sizes[8] / 2;   // 160000

    const int NFC = B * Nf * 32;  // 5,120,000
    const int NEC = B * Ne * 32;  // 10,240,000
    const int NVC = B * Nv * 32;  // 5,120,000

    // Workspace: xf0 [NFC] | xe0 [NEC] | mx [NEC ints]  => 102.4 MB
    float* ws  = (float*)d_ws;
    float* xf0 = ws;
    float* xe0 = ws + NFC;
    int*   mx  = (int*)(ws + NFC + NEC);

    float* oxf = (float*)d_out;               // holds xf1 then final xf
    float* oxe = oxf + NFC;                   // holds xe1 then final xe
    float* oxv = oxe + NEC;                   // holds xv0 then final xv

    const int T = 256;
    auto blk = [](int n) { return (n + 255) / 256; };

    // Input linears
    lin_lrelu<<<blk(NFC), T, 0, stream>>>(x_f, Wf, bf, xf0, B * Nf, 4);
    lin_lrelu<<<blk(NEC), T, 0, stream>>>(x_e, We, be, xe0, B * Ne, 6);
    lin_lrelu<<<blk(NVC), T, 0, stream>>>(x_v, Wv, bv, oxv, B * Nv, 3);  // xv0 in oxv

    // F2E: src xf0, dst xe0 -> oxe (= xe1)
    fill_i32<<<blk(NEC), T, 0, stream>>>(mx, NEC, SENTINEL);
    scatter_max<<<blk(E_fe * 128), T, 0, stream>>>(xf0, xe0, fe, E_fe, Nf, Ne, mx);
    mlp_res<<<blk(NEC), T, 0, stream>>>(xe0, mx, W_f2e, b_f2e, oxe, B * Ne);

    // E2V: src xe0, dst oxv(=xv0) -> oxv in-place (final xv)
    fill_i32<<<blk(NVC), T, 0, stream>>>(mx, NVC, SENTINEL);
    scatter_max<<<blk(E_ev * 128), T, 0, stream>>>(xe0, oxv, ev, E_ev, Ne, Nv, mx);
    mlp_res<<<blk(NVC), T, 0, stream>>>(oxv, mx, W_e2v, b_e2v, oxv, B * Nv);

    // F2F: src xf0, dst xf0 -> oxf (= xf1)
    fill_i32<<<blk(NFC), T, 0, stream>>>(mx, NFC, SENTINEL);
    scatter_max<<<blk(E_ff * 128), T, 0, stream>>>(xf0, xf0, ff, E_ff, Nf, Nf, mx);
    mlp_res<<<blk(NFC), T, 0, stream>>>(xf0, mx, W_ff, b_ff, oxf, B * Nf);

    // E2F: src oxe(=xe1), dst oxf(=xf1) -> oxf in-place (final xf)
    fill_i32<<<blk(NFC), T, 0, stream>>>(mx, NFC, SENTINEL);
    scatter_max<<<blk(E_ef * 128), T, 0, stream>>>(oxe, oxf, ef, E_ef, Ne, Nf, mx);
    mlp_res<<<blk(NFC), T, 0, stream>>>(oxf, mx, W_e2f, b_e2f, oxf, B * Nf);

    // V2E: src oxv(final xv), dst oxe(=xe1) -> oxe in-place (final xe)
    fill_i32<<<blk(NEC), T, 0, stream>>>(mx, NEC, SENTINEL);
    scatter_max<<<blk(E_ve * 128), T, 0, stream>>>(oxv, oxe, ve, E_ve, Nv, Ne, mx);
    mlp_res<<<blk(NEC), T, 0, stream>>>(oxe, mx, W_v2e, b_v2e, oxe, B * Ne);
}

// Round 3
// 638.025 us; speedup vs baseline: 1.3722x; 1.3722x over previous
//
#include <hip/hip_runtime.h>
#include <float.h>

#define LRELU(v) ((v) > 0.0f ? (v) : 0.01f * (v))

// ---------------------------------------------------------------------------
// Graph metadata (hardcoded to this problem's sizes):
//   g: 0=F2E (Nf->Ne), 1=E2V (Ne->Nv), 2=FF (Nf->Nf), 3=E2F (Ne->Nf), 4=V2E (Nv->Ne)
//   E:      160000, 160000, 240000, 160000, 160000   (total 880000)
//   Nd:      80000,  40000,  40000,  40000,  80000   (padded to x256: 80128/40192)
//   cntOff:      0,  80128, 120320, 160512, 200704   (total 280832 = 1097*256)
//   blkOff:      0,    313,    470,    627,    784   (total 1097 blocks)
//   csrOff:      0, 160000, 320000, 560000, 720000
// ---------------------------------------------------------------------------

__global__ void fill_i32(int* __restrict__ p, int n, int v) {
    int i = blockIdx.x * blockDim.x + threadIdx.x;
    if (i < n) p[i] = v;
}

// out[r, c] = lrelu(sum_k x[r,k] * W[k,c] + b[c]), c in [0,32)
__global__ void lin_lrelu(const float* __restrict__ x, const float* __restrict__ W,
                          const float* __restrict__ b, float* __restrict__ out,
                          int rows, int cin) {
    int idx = blockIdx.x * blockDim.x + threadIdx.x;
    if (idx >= rows * 32) return;
    int c = idx & 31;
    int r = idx >> 5;
    float acc = b[c];
    for (int k = 0; k < cin; ++k)
        acc = fmaf(x[r * cin + k], W[k * 32 + c], acc);
    out[idx] = LRELU(acc);
}

// Histogram of dst indices for all 5 graphs at once.
__global__ void hist5(const int* __restrict__ e0, const int* __restrict__ e1,
                      const int* __restrict__ e2, const int* __restrict__ e3,
                      const int* __restrict__ e4, int* __restrict__ cnt) {
    int idx = blockIdx.x * 256 + threadIdx.x;
    if (idx >= 880000) return;
    const int cum[6]  = {0, 160000, 320000, 560000, 720000, 880000};
    const int cOff[5] = {0, 80128, 120320, 160512, 200704};
    const int Eg[5]   = {160000, 160000, 240000, 160000, 160000};
    const int* eds[5] = {e0, e1, e2, e3, e4};
    int g = 0;
#pragma unroll
    for (int k = 1; k < 5; ++k) g += (idx >= cum[k]);
    int e = idx - cum[g];
    const int* ed = eds[g];
    int d = ed[Eg[g] + e];           // dst = row 1 of [2, E]
    atomicAdd(&cnt[cOff[g] + d], 1);
}

// Per-256-block exclusive scan; block totals to bsum. cnt regions are padded
// to multiples of 256 so blocks never straddle graph boundaries.
__global__ void scan_blocks(int* __restrict__ cnt, int* __restrict__ bsum) {
    __shared__ int buf[256];
    int t = threadIdx.x;
    int i = blockIdx.x * 256 + t;
    int v = cnt[i];
    buf[t] = v;
    __syncthreads();
    for (int off = 1; off < 256; off <<= 1) {
        int x = (t >= off) ? buf[t - off] : 0;
        __syncthreads();
        buf[t] += x;
        __syncthreads();
    }
    cnt[i] = buf[t] - v;            // exclusive prefix within block
    if (t == 255) bsum[blockIdx.x] = buf[255];
}

// Segmented exclusive scan of the 1097 block sums (5 segments), one block.
__global__ void scan_bsum(int* __restrict__ bsum) {
    __shared__ int buf[512];
    const int blkOff[5] = {0, 313, 470, 627, 784};
    const int nb[5]     = {313, 157, 157, 157, 313};
    int t = threadIdx.x;
    for (int g = 0; g < 5; ++g) {
        int v = (t < nb[g]) ? bsum[blkOff[g] + t] : 0;
        buf[t] = v;
        __syncthreads();
        for (int off = 1; off < 512; off <<= 1) {
            int x = (t >= off) ? buf[t - off] : 0;
            __syncthreads();
            buf[t] += x;
            __syncthreads();
        }
        if (t < nb[g]) bsum[blkOff[g] + t] = buf[t] - v;
        __syncthreads();
    }
}

// cnt[i] += scanned block offset -> global "starts"; duplicate into cursor.
__global__ void scan_add(int* __restrict__ cnt, const int* __restrict__ bsum,
                         int* __restrict__ cursor) {
    int i = blockIdx.x * 256 + threadIdx.x;
    int v = cnt[i] + bsum[blockIdx.x];
    cnt[i] = v;
    cursor[i] = v;
}

// Scatter src indices into CSR slots (order within a segment is irrelevant
// for min-reduction).
__global__ void fill_csr(const int* __restrict__ e0, const int* __restrict__ e1,
                         const int* __restrict__ e2, const int* __restrict__ e3,
                         const int* __restrict__ e4, int* __restrict__ cursor,
                         int* __restrict__ csr) {
    int idx = blockIdx.x * 256 + threadIdx.x;
    if (idx >= 880000) return;
    const int cum[6]   = {0, 160000, 320000, 560000, 720000, 880000};
    const int cOff[5]  = {0, 80128, 120320, 160512, 200704};
    const int csOff[5] = {0, 160000, 320000, 560000, 720000};
    const int Eg[5]    = {160000, 160000, 240000, 160000, 160000};
    const int* eds[5]  = {e0, e1, e2, e3, e4};
    int g = 0;
#pragma unroll
    for (int k = 1; k < 5; ++k) g += (idx >= cum[k]);
    int e = idx - cum[g];
    const int* ed = eds[g];
    int s = ed[e];
    int d = ed[Eg[g] + e];
    int pos = atomicAdd(&cursor[cOff[g] + d], 1);
    csr[csOff[g] + pos] = s;
}

// Fused BipartiteResMRConv:
//   maxes[d,b,c] = deg(d)>0 ? xdst[d,b,c] - min_{s in CSR(d)} xsrc[s,b,c] : 0
//   out[d,b,c]   = xdst + lrelu([xdst|maxes] @ W + bias)
// Block = 256 threads = 2 dst nodes x (4 batches x 32 channels).
// Each wave64 holds a single d -> no loop divergence within a wave.
// Safe for out == xdst (thread reads its own element before writing; the
// gather source xsrc never aliases out in this net's dataflow).
__global__ void conv_fused(const float* __restrict__ xsrc, const float* __restrict__ xdst,
                           const int* __restrict__ starts, const int* __restrict__ csr,
                           const float* __restrict__ W, const float* __restrict__ bias,
                           float* __restrict__ out, int Ns, int Nd) {
    __shared__ float sW[2048];        // 64 x 32
    __shared__ float sh[2][4][64];    // [which][batch][h]
    int t = threadIdx.x;
    for (int i = t; i < 2048; i += 256) sW[i] = W[i];
    int which = t >> 7;
    int b = (t >> 5) & 3;
    int c = t & 31;
    int d = blockIdx.x * 2 + which;
    float xv = 0.0f;
    if (d < Nd) {
        xv = xdst[(b * Nd + d) * 32 + c];
        int s0 = starts[d];
        int s1 = starts[d + 1];       // padded region guarantees starts[Nd] == E
        float mn = FLT_MAX;
        for (int j = s0; j < s1; ++j) {
            int s = csr[j];
            mn = fminf(mn, xsrc[(b * Ns + s) * 32 + c]);
        }
        sh[which][b][c] = xv;
        sh[which][b][32 + c] = (s1 > s0) ? (xv - mn) : 0.0f;
    }
    __syncthreads();
    if (d >= Nd) return;
    float acc = bias[c];
#pragma unroll
    for (int k = 0; k < 64; ++k)
        acc = fmaf(sh[which][b][k], sW[k * 32 + c], acc);
    out[(b * Nd + d) * 32 + c] = xv + LRELU(acc);
}

extern "C" void kernel_launch(void* const* d_in, const int* in_sizes, int n_in,
                              void* d_out, int out_size, void* d_ws, size_t ws_size,
                              hipStream_t stream) {
    const float* x_f = (const float*)d_in[0];
    const float* x_e = (const float*)d_in[1];
    const float* x_v = (const float*)d_in[2];
    // d_in[3] = index_id (identity arange) — unused
    const int* fe = (const int*)d_in[4];
    const int* ev = (const int*)d_in[5];
    const int* ff = (const int*)d_in[6];
    const int* ef = (const int*)d_in[7];
    const int* ve = (const int*)d_in[8];
    const float* Wf = (const float*)d_in[9];
    const float* bf = (const float*)d_in[10];
    const float* We = (const float*)d_in[11];
    const float* be = (const float*)d_in[12];
    const float* Wv = (const float*)d_in[13];
    const float* bv = (const float*)d_in[14];
    const float* W_f2e = (const float*)d_in[15];
    const float* b_f2e = (const float*)d_in[16];
    const float* W_e2v = (const float*)d_in[17];
    const float* b_e2v = (const float*)d_in[18];
    const float* W_ff  = (const float*)d_in[19];
    const float* b_ff  = (const float*)d_in[20];
    const float* W_e2f = (const float*)d_in[21];
    const float* b_e2f = (const float*)d_in[22];
    const float* W_v2e = (const float*)d_in[23];
    const float* b_v2e = (const float*)d_in[24];

    const int B = 4, Nf = 40000, Ne = 80000, Nv = 40000;
    const int NFC = B * Nf * 32;  // 5,120,000
    const int NEC = B * Ne * 32;  // 10,240,000
    const int NVC = B * Nv * 32;  // 5,120,000

    const int CNT_TOTAL = 280832;   // 1097 * 256
    const int NBLK = 1097;
    const int E_TOTAL = 880000;

    // Workspace: xf0 | xe0 | cnt | cursor | bsum | csr  => ~67 MB
    float* ws  = (float*)d_ws;
    float* xf0 = ws;
    float* xe0 = ws + NFC;
    int* cnt    = (int*)(ws + NFC + NEC);
    int* cursor = cnt + CNT_TOTAL;
    int* bsum   = cursor + CNT_TOTAL;
    int* csr    = bsum + 1152;

    float* oxf = (float*)d_out;        // xf1 then final xf
    float* oxe = oxf + NFC;            // xe1 then final xe
    float* oxv = oxe + NEC;            // xv0 then final xv

    const int T = 256;
    auto blk = [](int n) { return (n + 255) / 256; };

    // Input linears
    lin_lrelu<<<blk(NFC), T, 0, stream>>>(x_f, Wf, bf, xf0, B * Nf, 4);
    lin_lrelu<<<blk(NEC), T, 0, stream>>>(x_e, We, be, xe0, B * Ne, 6);
    lin_lrelu<<<blk(NVC), T, 0, stream>>>(x_v, Wv, bv, oxv, B * Nv, 3);  // xv0

    // Batched CSR build for all 5 graphs
    fill_i32<<<blk(CNT_TOTAL), T, 0, stream>>>(cnt, CNT_TOTAL, 0);
    hist5<<<blk(E_TOTAL), T, 0, stream>>>(fe, ev, ff, ef, ve, cnt);
    scan_blocks<<<NBLK, 256, 0, stream>>>(cnt, bsum);
    scan_bsum<<<1, 512, 0, stream>>>(bsum);
    scan_add<<<NBLK, 256, 0, stream>>>(cnt, bsum, cursor);
    fill_csr<<<blk(E_TOTAL), T, 0, stream>>>(fe, ev, ff, ef, ve, cursor, csr);

    // Per-graph starts/csr views
    int* st_f2e = cnt;            int* cs_f2e = csr;
    int* st_e2v = cnt + 80128;    int* cs_e2v = csr + 160000;
    int* st_ff  = cnt + 120320;   int* cs_ff  = csr + 320000;
    int* st_e2f = cnt + 160512;   int* cs_e2f = csr + 560000;
    int* st_v2e = cnt + 200704;   int* cs_v2e = csr + 720000;

    // F2E: src xf0, dst xe0 -> oxe (= xe1)
    conv_fused<<<(Ne + 1) / 2, 256, 0, stream>>>(xf0, xe0, st_f2e, cs_f2e,
                                                 W_f2e, b_f2e, oxe, Nf, Ne);
    // E2V: src xe0, dst oxv(=xv0) -> oxv in place (final xv)
    conv_fused<<<(Nv + 1) / 2, 256, 0, stream>>>(xe0, oxv, st_e2v, cs_e2v,
                                                 W_e2v, b_e2v, oxv, Ne, Nv);
    // F2F: src xf0, dst xf0 -> oxf (= xf1)
    conv_fused<<<(Nf + 1) / 2, 256, 0, stream>>>(xf0, xf0, st_ff, cs_ff,
                                                 W_ff, b_ff, oxf, Nf, Nf);
    // E2F: src oxe(=xe1), dst oxf(=xf1) -> oxf in place (final xf)
    conv_fused<<<(Nf + 1) / 2, 256, 0, stream>>>(oxe, oxf, st_e2f, cs_e2f,
                                                 W_e2f, b_e2f, oxf, Ne, Nf);
    // V2E: src oxv(final xv), dst oxe(=xe1) -> oxe in place (final xe)
    conv_fused<<<(Ne + 1) / 2, 256, 0, stream>>>(oxv, oxe, st_v2e, cs_v2e,
                                                 W_v2e, b_v2e, oxe, Nv, Ne);
}